// Round 3
// baseline (162.861 us; speedup 1.0000x reference)
//
#include <hip/hip_runtime.h>
#include <stdint.h>

#define N      6144
#define F      128
#define D      32
#define H      4
#define HID    128
#define NP1    6145
#define CHK    128      // sort chunk size
#define NCHK   48       // chunks per head
#define NSEG   64       // segments per head
#define SEGL   96       // rows per segment
#define NBLK   256
#define NTHR   512

// ---- device scratch (module globals; d_ws unused) ----
__device__ float    g_Wh[(size_t)N * HID];
__device__ float    g_es[H * N];
__device__ float    g_ed[H * N];
__device__ uint64_t g_keys[H * N];       // chunk-sorted keys
__device__ float    g_dsv[H * N];        // globally sorted d values
__device__ float    g_WhP[(size_t)H * D * N];
__device__ float    g_SEG[H * 66 * NSEG];
__device__ float    g_VEC[(size_t)H * NP1 * 64];  // [h][k][c]: c<32 u*wh pfx, c>=32 v*wh pfx
__device__ float    g_SCL[(size_t)H * NP1 * 2];   // [h][k][{u1,v1}]
__device__ float    g_PART[H * NSEG * D];

// ---- grid barrier state (zero-init in .bss; protocol self-resets) ----
#define NSLOT 8
__device__ unsigned g_leaf[NSLOT][16][32];
__device__ unsigned g_master[NSLOT][32];
__device__ unsigned g_dep[NSLOT][32];

__device__ __forceinline__ void gbar(int slot) {
    __syncthreads();
    if (threadIdx.x == 0) {
        int leaf = blockIdx.x >> 4;   // 16 groups of 16 blocks
        unsigned p = __hip_atomic_fetch_add(&g_leaf[slot][leaf][0], 1u,
                        __ATOMIC_ACQ_REL, __HIP_MEMORY_SCOPE_AGENT);
        if (p == 15u) {
            __hip_atomic_fetch_add(&g_master[slot][0], 1u,
                        __ATOMIC_ACQ_REL, __HIP_MEMORY_SCOPE_AGENT);
        }
        unsigned iter = 0;
        while (__hip_atomic_load(&g_master[slot][0], __ATOMIC_RELAXED,
                        __HIP_MEMORY_SCOPE_AGENT) < 16u) {
            __builtin_amdgcn_s_sleep(2);
            if (++iter > (1u << 22)) break;   // safety: never hang
        }
        (void)__hip_atomic_load(&g_master[slot][0], __ATOMIC_ACQUIRE,
                        __HIP_MEMORY_SCOPE_AGENT);
        unsigned q = __hip_atomic_fetch_add(&g_dep[slot][0], 1u,
                        __ATOMIC_ACQ_REL, __HIP_MEMORY_SCOPE_AGENT);
        if (q == (unsigned)(NBLK - 1)) {      // last departer resets for next replay
            for (int l = 0; l < 16; ++l)
                __hip_atomic_store(&g_leaf[slot][l][0], 0u, __ATOMIC_RELAXED,
                                   __HIP_MEMORY_SCOPE_AGENT);
            __hip_atomic_store(&g_master[slot][0], 0u, __ATOMIC_RELAXED,
                               __HIP_MEMORY_SCOPE_AGENT);
            __hip_atomic_store(&g_dep[slot][0], 0u, __ATOMIC_RELAXED,
                               __HIP_MEMORY_SCOPE_AGENT);
        }
    }
    __syncthreads();
}

__device__ __forceinline__ uint32_t f2mono(float f) {
    uint32_t u = __float_as_uint(f);
    return (u & 0x80000000u) ? ~u : (u | 0x80000000u);
}

union SmemU {
    struct { uint64_t k[CHK]; int part[CHK][4]; } p2;
    struct { uint64_t ks[N]; int part[SEGL][5]; int jj[SEGL]; int rk[SEGL]; } p3;
    struct { float e1[SEGL]; float e2[SEGL]; } p4a;
    struct { float e1[SEGL]; float e2[SEGL]; float tile[SEGL * 69]; } p4c;
    struct { float dsv[N]; float wred[8][32]; } p5;
    struct { float hm[HID]; } p6;
};

__global__ __launch_bounds__(NTHR) void mega(
        const float* __restrict__ x, const float* __restrict__ W,
        const float* __restrict__ a_src, const float* __restrict__ a_dst,
        const float* __restrict__ W_fc, const float* __restrict__ b_fc,
        float* __restrict__ out)
{
    __shared__ SmemU sm;
    const int tid = threadIdx.x;
    const int bid = blockIdx.x;
    const int lane = tid & 63;
    const int wv = tid >> 6;

    // ================= P1: Wh = x@W, e_s/e_d =================
    {
        int col = tid & 127;
        int rt  = __builtin_amdgcn_readfirstlane(tid >> 7);  // 0..3 wave-uniform
        int h = col >> 5, d = col & 31;
        int nbase = bid * 24 + rt * 6;
        const float* xb = x + (size_t)nbase * F;
        const float* Wp = W + h * (F * D) + d;
        float acc[6] = {0.f, 0.f, 0.f, 0.f, 0.f, 0.f};
#pragma unroll 4
        for (int f = 0; f < F; ++f) {
            float w = Wp[f * D];
#pragma unroll
            for (int r = 0; r < 6; ++r)
                acc[r] = fmaf(xb[r * F + f], w, acc[r]);
        }
        float as = a_src[col], ad = a_dst[col];
#pragma unroll
        for (int r = 0; r < 6; ++r) {
            int n = nbase + r;
            g_Wh[(size_t)n * HID + col] = acc[r];
            float ts = acc[r] * as, td = acc[r] * ad;
#pragma unroll
            for (int m = 1; m < 32; m <<= 1) {
                ts += __shfl_xor(ts, m);
                td += __shfl_xor(td, m);
            }
            if ((lane & 31) == 0) { g_es[h * N + n] = ts; g_ed[h * N + n] = td; }
        }
    }
    gbar(0);

    // ================= P2: sort 128-key chunks (all-pairs rank) =================
    if (bid < H * NCHK) {
        int h = bid / NCHK, c = bid % NCHK;
        const float* edh = g_ed + h * N;
        if (tid < CHK) {
            int j = c * CHK + tid;
            sm.p2.k[tid] = (((uint64_t)f2mono(edh[j])) << 13) | (uint32_t)j;
        }
        __syncthreads();
        {
            int it = tid & 127, q = tid >> 7;   // q 0..3, 32 compares each
            uint64_t myk = sm.p2.k[it];
            int cnt = 0;
            for (int s2 = q * 32; s2 < q * 32 + 32; ++s2)
                cnt += (sm.p2.k[s2] < myk) ? 1 : 0;
            sm.p2.part[it][q] = cnt;
        }
        __syncthreads();
        if (tid < CHK) {
            int rank = sm.p2.part[tid][0] + sm.p2.part[tid][1]
                     + sm.p2.part[tid][2] + sm.p2.part[tid][3];
            g_keys[h * N + c * CHK + rank] = sm.p2.k[tid];
        }
    }
    gbar(1);

    // ========== P3: global rank (+ write ds, gather WhP directly) ==========
    {
        int h = bid >> 6;
        int sbase = (bid & 63) * SEGL;
        const uint64_t* kh = g_keys + h * N;
        for (int r = tid; r < N; r += NTHR) sm.p3.ks[r] = kh[r];
        __syncthreads();
        if (tid < 480) {
            int it = tid % 96, q = tid / 96;   // q 0..4, ~10 chunks each
            int slot = sbase + it;
            uint64_t myk = sm.p3.ks[slot];
            int cown = slot >> 7;
            int cnt = 0;
            int c0 = q * 10, c1 = (c0 + 10 < NCHK) ? c0 + 10 : NCHK;
            for (int cc = c0; cc < c1; ++cc) {
                if (cc == cown) continue;
                int base = cc * CHK;
                int pos = 0;
#pragma unroll
                for (int st = CHK; st >= 1; st >>= 1) {
                    int np = pos + st;
                    if (np <= CHK && sm.p3.ks[base + np - 1] < myk) pos = np;
                }
                cnt += pos;
            }
            sm.p3.part[it][q] = cnt;
        }
        __syncthreads();
        if (tid < SEGL) {
            int slot = sbase + tid;
            uint64_t myk = sm.p3.ks[slot];
            int rank = (slot & 127);
            for (int q = 0; q < 5; ++q) rank += sm.p3.part[tid][q];
            uint32_t m = (uint32_t)(myk >> 13);
            uint32_t u = (m & 0x80000000u) ? (m ^ 0x80000000u) : ~m;
            g_dsv[h * N + rank] = __uint_as_float(u);
            sm.p3.rk[tid] = rank;
            sm.p3.jj[tid] = (int)(myk & 8191u);
        }
        __syncthreads();
        if (tid < 384) {
            int it = tid % 96, g = tid / 96;   // g 0..3 -> d range g*8..g*8+7
            int rank = sm.p3.rk[it];
            int j = sm.p3.jj[it];
            const float4* src = (const float4*)&g_Wh[(size_t)j * HID + h * D + g * 8];
            float4 A = src[0], B = src[1];
            float vv[8] = {A.x, A.y, A.z, A.w, B.x, B.y, B.z, B.w};
            float* dst = g_WhP + (size_t)h * D * N + rank;
#pragma unroll
            for (int u2 = 0; u2 < 8; ++u2)
                dst[(size_t)(g * 8 + u2) * N] = vv[u2];
        }
    }
    gbar(2);

    // ================= P4a: per-segment sums of 66 components =================
    {
        int h = bid >> 6, seg = bid & 63;
        int r0 = seg * SEGL;
        if (tid < SEGL) {
            float dv = g_dsv[h * N + r0 + tid];
            sm.p4a.e1[tid] = expf(0.01f * dv);
            sm.p4a.e2[tid] = expf(dv);
        }
        __syncthreads();
        for (int k = 0; k < 9; ++k) {
            int c = wv + 8 * k;
            if (c > 65) break;
            float sum;
            if (c < 64) {
                int fam = c >> 5, d = c & 31;
                const float* wp = g_WhP + (size_t)(h * D + d) * N + r0;
                const float* e = fam ? sm.p4a.e2 : sm.p4a.e1;
                float v1 = e[lane] * wp[lane];
                float v2 = (lane < 32) ? e[64 + lane] * wp[64 + lane] : 0.f;
                sum = v1 + v2;
            } else {
                const float* e = (c == 65) ? sm.p4a.e2 : sm.p4a.e1;
                sum = e[lane] + ((lane < 32) ? e[64 + lane] : 0.f);
            }
#pragma unroll
            for (int m = 1; m < 64; m <<= 1) sum += __shfl_xor(sum, m);
            if (lane == 0) g_SEG[(h * 66 + c) * NSEG + seg] = sum;
        }
    }
    gbar(3);

    // ===== P4c: segment offsets + intra-segment scan -> row-major prefix table =====
    {
        int h = bid >> 6, seg = bid & 63;
        int r0 = seg * SEGL;
        if (tid < SEGL) {
            float dv = g_dsv[h * N + r0 + tid];
            sm.p4c.e1[tid] = expf(0.01f * dv);
            sm.p4c.e2[tid] = expf(dv);
        }
        __syncthreads();
        for (int k = 0; k < 9; ++k) {
            int c = wv + 8 * k;
            if (c > 65) break;
            // offset = sum of seg-sums of segments < seg (butterfly over lanes=segs)
            float sv = g_SEG[(h * 66 + c) * NSEG + lane];
            float msk = (lane < seg) ? sv : 0.f;
#pragma unroll
            for (int m = 1; m < 64; m <<= 1) msk += __shfl_xor(msk, m);
            float off = msk;
            // products
            float p_lo, p_hi;
            if (c < 64) {
                int fam = c >> 5, d = c & 31;
                const float* wp = g_WhP + (size_t)(h * D + d) * N + r0;
                const float* e = fam ? sm.p4c.e2 : sm.p4c.e1;
                p_lo = e[lane] * wp[lane];
                p_hi = (lane < 32) ? e[64 + lane] * wp[64 + lane] : 0.f;
            } else {
                const float* e = (c == 65) ? sm.p4c.e2 : sm.p4c.e1;
                p_lo = e[lane];
                p_hi = (lane < 32) ? e[64 + lane] : 0.f;
            }
            // inclusive scans (wave64 shfl_up)
            float s_lo = p_lo;
#pragma unroll
            for (int m = 1; m < 64; m <<= 1) {
                float t = __shfl_up(s_lo, m);
                if (lane >= m) s_lo += t;
            }
            float tot_lo = __shfl(s_lo, 63);
            float s_hi = p_hi;
#pragma unroll
            for (int m = 1; m < 32; m <<= 1) {
                float t = __shfl_up(s_hi, m);
                if (lane >= m) s_hi += t;
            }
            sm.p4c.tile[lane * 69 + c] = off + s_lo;
            if (lane < 32) sm.p4c.tile[(64 + lane) * 69 + c] = off + tot_lo + s_hi;
        }
        __syncthreads();
        float* vec = g_VEC + (size_t)h * NP1 * 64;
        for (int t = tid; t < SEGL * 64; t += NTHR) {
            int row = t >> 6, c = t & 63;
            vec[(size_t)(r0 + row + 1) * 64 + c] = sm.p4c.tile[row * 69 + c];
        }
        float* scl = g_SCL + (size_t)h * NP1 * 2;
        for (int t = tid; t < SEGL * 2; t += NTHR) {
            int row = t >> 1, c = t & 1;
            scl[(size_t)(r0 + row + 1) * 2 + c] = sm.p4c.tile[row * 69 + 64 + c];
        }
        if (seg == 0) {
            if (tid < 64) vec[tid] = 0.f;
            else if (tid < 66) scl[tid - 64] = 0.f;
        }
    }
    gbar(4);

    // ================= P5: per-row eval (wave per item) =================
    {
        int h = bid >> 6;
        int ibase = (bid & 63) * SEGL;
        const float* dsh = g_dsv + h * N;
        for (int r = tid; r < N; r += NTHR) sm.p5.dsv[r] = dsh[r];
        __syncthreads();
        const float* vec = g_VEC + (size_t)h * NP1 * 64;
        const float* scl = g_SCL + (size_t)h * NP1 * 2;
        float vt = vec[(size_t)N * 64 + lane];
        float vt_o = __shfl_xor(vt, 32);           // for lanes<32: v-family totals
        float v1T = scl[(size_t)N * 2 + 1];
        float acc = 0.f;
        for (int t = 0; t < 12; ++t) {
            int i = ibase + wv * 12 + t;
            float s = g_es[h * N + i];
            float nst = -s;
            int k = 0;
#pragma unroll
            for (int st = 4096; st >= 1; st >>= 1) {
                int np = k + st;
                if (np <= N && sm.p5.dsv[np - 1] <= nst) k = np;
            }
            float e1 = expf(0.01f * s), e2 = expf(s);
            float pu1 = scl[(size_t)k * 2 + 0];
            float pv1 = scl[(size_t)k * 2 + 1];
            float inv = 1.0f / (e1 * pu1 + e2 * (v1T - pv1));
            float val = vec[(size_t)k * 64 + lane];
            float val_o = __shfl_xor(val, 32);
            float num = e1 * val + e2 * (vt_o - val_o);   // valid for lanes<32
            acc += fmaxf(num, 0.f) * inv;                 // relu(elu(x)) == relu(x)
        }
        if (lane < 32) sm.p5.wred[wv][lane] = acc;
        __syncthreads();
        if (tid < 32) {
            float p = 0.f;
#pragma unroll
            for (int ww = 0; ww < 8; ++ww) p += sm.p5.wred[ww][tid];
            g_PART[((bid >> 6) * NSEG + (bid & 63)) * D + tid] = p;
        }
    }
    gbar(5);

    // ================= P6: mean + final linear (block 0) =================
    if (bid == 0) {
        if (tid < HID) {
            int hh = tid >> 5, dd = tid & 31;
            float sum = 0.f;
            for (int s2 = 0; s2 < NSEG; ++s2)
                sum += g_PART[(hh * NSEG + s2) * D + dd];
            sm.p6.hm[tid] = sum * (1.0f / (float)N);
        }
        __syncthreads();
        if (tid < 128) {
            float y = b_fc[tid];
#pragma unroll 8
            for (int c = 0; c < 128; ++c)
                y = fmaf(sm.p6.hm[c], W_fc[c * 128 + tid], y);
            out[tid] = y;
        }
    }
}

extern "C" void kernel_launch(void* const* d_in, const int* in_sizes, int n_in,
                              void* d_out, int out_size, void* d_ws, size_t ws_size,
                              hipStream_t stream) {
    (void)in_sizes; (void)n_in; (void)d_ws; (void)ws_size; (void)out_size;
    const float* x     = (const float*)d_in[0];
    const float* W     = (const float*)d_in[1];
    const float* a_src = (const float*)d_in[2];
    const float* a_dst = (const float*)d_in[3];
    const float* W_fc  = (const float*)d_in[4];
    const float* b_fc  = (const float*)d_in[5];
    float* out = (float*)d_out;

    mega<<<dim3(NBLK), dim3(NTHR), 0, stream>>>(x, W, a_src, a_dst, W_fc, b_fc, out);
}